// Round 4
// baseline (114.912 us; speedup 1.0000x reference)
//
#include <hip/hip_runtime.h>

// Native clang vector type — accepted by __builtin_nontemporal_{load,store},
// lowers to global_{load,store}_dwordx4 with nt.
typedef float f32x4 __attribute__((ext_vector_type(4)));

// i0e(x) = exp(-|x|) * I0(x), Abramowitz & Stegun 9.8.1 / 9.8.2,
// matching the JAX reference's branch structure exactly.
__device__ __forceinline__ float i0e_scalar(float x) {
    float ax = fabsf(x);

    // ---- small branch: exp(-ax) * poly((ax/3.75)^2), ascending-coeff Horner
    float t = ax * (1.0f / 3.75f);
    t = t * t;
    float ps = 0.0045813f;
    ps = fmaf(ps, t, 0.0360768f);
    ps = fmaf(ps, t, 0.2659732f);
    ps = fmaf(ps, t, 1.2067492f);
    ps = fmaf(ps, t, 3.0899424f);
    ps = fmaf(ps, t, 3.5156229f);
    ps = fmaf(ps, t, 1.0f);
    float sm = __expf(-ax) * ps;

    // ---- large branch: poly(3.75/ax_l) / sqrt(ax_l), ax_l = max(ax, 3.75)
    float axl = fmaxf(ax, 3.75f);
    float u = 3.75f * __builtin_amdgcn_rcpf(axl);   // v_rcp_f32, ~1 ulp
    float pl = 0.00392377f;
    pl = fmaf(pl, u, -0.01647633f);
    pl = fmaf(pl, u, 0.02635537f);
    pl = fmaf(pl, u, -0.02057706f);
    pl = fmaf(pl, u, 0.00916281f);
    pl = fmaf(pl, u, -0.00157565f);
    pl = fmaf(pl, u, 0.00225319f);
    pl = fmaf(pl, u, 0.01328592f);
    pl = fmaf(pl, u, 0.39894228f);
    float lg = pl * __builtin_amdgcn_rsqf(axl);     // v_rsq_f32

    return (ax <= 3.75f) ? sm : lg;
}

__device__ __forceinline__ f32x4 i0e_vec4(f32x4 v) {
    f32x4 r;
    r.x = i0e_scalar(v.x);
    r.y = i0e_scalar(v.y);
    r.z = i0e_scalar(v.z);
    r.w = i0e_scalar(v.w);
    return r;
}

__global__ __launch_bounds__(256) void ive_i0e_kernel(
        const float* __restrict__ in, float* __restrict__ out, int n) {
    const int n4 = n >> 2;
    const int tid = blockIdx.x * blockDim.x + threadIdx.x;
    const int stride = gridDim.x * blockDim.x;
    const f32x4* __restrict__ in4 = reinterpret_cast<const f32x4*>(in);
    f32x4* __restrict__ out4 = reinterpret_cast<f32x4*>(out);

    // 4x-unrolled grid-stride: all four nt loads in flight before any compute.
    int i = tid;
    for (; i + 3 * stride < n4; i += 4 * stride) {
        f32x4 a0 = __builtin_nontemporal_load(&in4[i]);
        f32x4 a1 = __builtin_nontemporal_load(&in4[i + stride]);
        f32x4 a2 = __builtin_nontemporal_load(&in4[i + 2 * stride]);
        f32x4 a3 = __builtin_nontemporal_load(&in4[i + 3 * stride]);
        f32x4 r0 = i0e_vec4(a0);
        f32x4 r1 = i0e_vec4(a1);
        f32x4 r2 = i0e_vec4(a2);
        f32x4 r3 = i0e_vec4(a3);
        __builtin_nontemporal_store(r0, &out4[i]);
        __builtin_nontemporal_store(r1, &out4[i + stride]);
        __builtin_nontemporal_store(r2, &out4[i + 2 * stride]);
        __builtin_nontemporal_store(r3, &out4[i + 3 * stride]);
    }
    for (; i < n4; i += stride) {
        f32x4 a = __builtin_nontemporal_load(&in4[i]);
        __builtin_nontemporal_store(i0e_vec4(a), &out4[i]);
    }

    // scalar tail (n % 4 != 0 — not hit for 64*1024*1024 but keep it correct)
    const int tail = n4 << 2;
    for (int j = tail + tid; j < n; j += stride) {
        out[j] = i0e_scalar(in[j]);
    }
}

extern "C" void kernel_launch(void* const* d_in, const int* in_sizes, int n_in,
                              void* d_out, int out_size, void* d_ws, size_t ws_size,
                              hipStream_t stream) {
    const float* z = (const float*)d_in[0];
    float* out = (float*)d_out;
    const int n = in_sizes[0];

    const int block = 256;
    int grid = (n / 4 + block - 1) / block;
    if (grid > 2048) grid = 2048;   // grid-stride; 8 blocks/CU across 256 CUs
    if (grid < 1) grid = 1;

    ive_i0e_kernel<<<grid, block, 0, stream>>>(z, out, n);
}

// Round 5
// 92.960 us; speedup vs baseline: 1.2361x; 1.2361x over previous
//
#include <hip/hip_runtime.h>

// Native clang vector type — accepted by __builtin_nontemporal_{load,store},
// lowers to global_{load,store}_dwordx4 with nt.
typedef float f32x4 __attribute__((ext_vector_type(4)));

// i0e(x) = exp(-|x|) * I0(x), Abramowitz & Stegun 9.8.1 / 9.8.2,
// matching the JAX reference's branch structure exactly.
__device__ __forceinline__ float i0e_scalar(float x) {
    float ax = fabsf(x);

    // ---- small branch: exp(-ax) * poly((ax/3.75)^2), ascending-coeff Horner
    float t = ax * (1.0f / 3.75f);
    t = t * t;
    float ps = 0.0045813f;
    ps = fmaf(ps, t, 0.0360768f);
    ps = fmaf(ps, t, 0.2659732f);
    ps = fmaf(ps, t, 1.2067492f);
    ps = fmaf(ps, t, 3.0899424f);
    ps = fmaf(ps, t, 3.5156229f);
    ps = fmaf(ps, t, 1.0f);
    float sm = __expf(-ax) * ps;

    // ---- large branch: poly(3.75/ax_l) / sqrt(ax_l), ax_l = max(ax, 3.75)
    float axl = fmaxf(ax, 3.75f);
    float u = 3.75f * __builtin_amdgcn_rcpf(axl);   // v_rcp_f32, ~1 ulp
    float pl = 0.00392377f;
    pl = fmaf(pl, u, -0.01647633f);
    pl = fmaf(pl, u, 0.02635537f);
    pl = fmaf(pl, u, -0.02057706f);
    pl = fmaf(pl, u, 0.00916281f);
    pl = fmaf(pl, u, -0.00157565f);
    pl = fmaf(pl, u, 0.00225319f);
    pl = fmaf(pl, u, 0.01328592f);
    pl = fmaf(pl, u, 0.39894228f);
    float lg = pl * __builtin_amdgcn_rsqf(axl);     // v_rsq_f32

    return (ax <= 3.75f) ? sm : lg;
}

__device__ __forceinline__ f32x4 i0e_vec4(f32x4 v) {
    f32x4 r;
    r.x = i0e_scalar(v.x);
    r.y = i0e_scalar(v.y);
    r.z = i0e_scalar(v.z);
    r.w = i0e_scalar(v.w);
    return r;
}

__global__ __launch_bounds__(256) void ive_i0e_kernel(
        const float* __restrict__ in, float* __restrict__ out, int n) {
    const int n4 = n >> 2;
    const int t = threadIdx.x;
    const f32x4* __restrict__ in4 = reinterpret_cast<const f32x4*>(in);
    f32x4* __restrict__ out4 = reinterpret_cast<f32x4*>(out);

    // Block-contiguous chunks: 1024 f32x4 = 16 KB per chunk. Thread t handles
    // base+t, +256, +512, +768 — four coalesced wave-accesses within ONE
    // contiguous 16 KB window (DRAM-row friendly), all four loads in flight.
    const int nchunk = n4 >> 10;
    for (int c = blockIdx.x; c < nchunk; c += gridDim.x) {
        const int base = (c << 10) + t;
        f32x4 a0 = __builtin_nontemporal_load(&in4[base]);
        f32x4 a1 = __builtin_nontemporal_load(&in4[base + 256]);
        f32x4 a2 = __builtin_nontemporal_load(&in4[base + 512]);
        f32x4 a3 = __builtin_nontemporal_load(&in4[base + 768]);
        f32x4 r0 = i0e_vec4(a0);
        f32x4 r1 = i0e_vec4(a1);
        f32x4 r2 = i0e_vec4(a2);
        f32x4 r3 = i0e_vec4(a3);
        __builtin_nontemporal_store(r0, &out4[base]);
        __builtin_nontemporal_store(r1, &out4[base + 256]);
        __builtin_nontemporal_store(r2, &out4[base + 512]);
        __builtin_nontemporal_store(r3, &out4[base + 768]);
    }

    // remainder f32x4 elements (none for 64M, but keep general)
    const int rem = nchunk << 10;
    const int gtid = blockIdx.x * blockDim.x + t;
    const int gstride = gridDim.x * blockDim.x;
    for (int i = rem + gtid; i < n4; i += gstride) {
        f32x4 a = __builtin_nontemporal_load(&in4[i]);
        __builtin_nontemporal_store(i0e_vec4(a), &out4[i]);
    }

    // scalar tail (n % 4 != 0 — not hit here but keep it correct)
    const int tail = n4 << 2;
    for (int j = tail + gtid; j < n; j += gstride) {
        out[j] = i0e_scalar(in[j]);
    }
}

extern "C" void kernel_launch(void* const* d_in, const int* in_sizes, int n_in,
                              void* d_out, int out_size, void* d_ws, size_t ws_size,
                              hipStream_t stream) {
    const float* z = (const float*)d_in[0];
    float* out = (float*)d_out;
    const int n = in_sizes[0];

    const int block = 256;
    int grid = (n / 4 + block - 1) / block;
    if (grid > 2048) grid = 2048;   // ~8 blocks/CU across 256 CUs
    if (grid < 1) grid = 1;

    ive_i0e_kernel<<<grid, block, 0, stream>>>(z, out, n);
}